// Round 8
// baseline (209.807 us; speedup 1.0000x reference)
//
#include <hip/hip_runtime.h>
#include <stdint.h>
#include <math.h>

#define NROWS 8192
#define DDIM  256

constexpr float INV_T = 1.0f / 0.07f;   // fixed LSE max M0 = 1/T (|logit| <= ~1/T)
constexpr float LOG2E = 1.44269504f;
constexpr float K1    = INV_T * LOG2E;  // exp2 arg: fma(acc, K1, -K1)

typedef __bf16 bf16x8 __attribute__((ext_vector_type(8)));
typedef float  f32x4  __attribute__((ext_vector_type(4)));

__device__ inline uint16_t f2bf(float f) {
    uint32_t u = __float_as_uint(f);
    u += 0x7fffu + ((u >> 16) & 1u);    // RNE
    return (uint16_t)(u >> 16);
}

// Kernel 1: unit-normalize rows of q and k (bf16 out) + fp32 paired cosine l_pos/T.
// Blocks 0..31 also zero the gpl atomic accumulator (ws is poisoned 0xAA each call).
__global__ __launch_bounds__(256) void norm_lpos_kernel(
    const float* __restrict__ fq, const float* __restrict__ fk,
    uint16_t* __restrict__ qb, uint16_t* __restrict__ kb,
    float* __restrict__ lpT, float* __restrict__ gpl)
{
    const int wave = threadIdx.x >> 6;
    const int lane = threadIdx.x & 63;
    const int row  = blockIdx.x * 4 + wave;

    if (blockIdx.x < 32) gpl[blockIdx.x * 256 + threadIdx.x] = 0.f;

    float4 vq = ((const float4*)(fq + (size_t)row * DDIM))[lane];
    float4 vk = ((const float4*)(fk + (size_t)row * DDIM))[lane];
    float sq = vq.x*vq.x + vq.y*vq.y + vq.z*vq.z + vq.w*vq.w;
    float sk = vk.x*vk.x + vk.y*vk.y + vk.z*vk.z + vk.w*vk.w;
    float dp = vq.x*vk.x + vq.y*vk.y + vq.z*vk.z + vq.w*vk.w;
    #pragma unroll
    for (int m = 1; m < 64; m <<= 1) {
        sq += __shfl_xor(sq, m, 64);
        sk += __shfl_xor(sk, m, 64);
        dp += __shfl_xor(dp, m, 64);
    }
    float rq = rsqrtf(sq), rk = rsqrtf(sk);   // norms ~16; EPS clamp unreachable

    ushort4 oq, ok;
    oq.x = f2bf(vq.x * rq); oq.y = f2bf(vq.y * rq); oq.z = f2bf(vq.z * rq); oq.w = f2bf(vq.w * rq);
    ok.x = f2bf(vk.x * rk); ok.y = f2bf(vk.y * rk); ok.z = f2bf(vk.z * rk); ok.w = f2bf(vk.w * rk);
    ((ushort4*)(qb + (size_t)row * DDIM))[lane] = oq;
    ((ushort4*)(kb + (size_t)row * DDIM))[lane] = ok;
    if (lane == 0) lpT[row] = dp * rq * rk * INV_T;   // == sim[i,i]/T, fp32-exact
}

// Kernel 2: BARRIER-FREE fused GEMM + fixed-max sum-of-exp.
// Each block: one 128x128 tile (2x2 waves, 64x64/wave), K=256 in 8 phases.
// MFMA fragments are loaded DIRECTLY from global to VGPRs (the A/B fragment
// layout maps to 16 cache lines per global_load_dwordx4 — fully coalesced);
// no LDS, no __syncthreads in the compute path -> no block-wide vmcnt(0)
// drains (the structural stall of rounds 1-7). Triple-buffered fragment
// prefetch (distance 2) gives each wave ~2 phases of load latency slack,
// scheduled per-wave by compiler vmcnt. L1 serves the pairwise-shared
// fragment lines between the block's waves. Row partials via atomicAdd.
// No diag masking (diag term == exp(l_pos/T - M0) belongs in the sum exactly).
__global__ __launch_bounds__(256)
__attribute__((amdgpu_waves_per_eu(2, 2)))   // ~190 VGPR needed: allow the full
void nce_main_kernel(                        // 256-reg budget, don't spill at 128
    const uint16_t* __restrict__ qb, const uint16_t* __restrict__ kb,
    float* __restrict__ gpl)
{
    const int tid    = threadIdx.x;
    const int wave   = tid >> 6;
    const int lane   = tid & 63;
    const int quad   = lane >> 4;
    const int lanelo = lane & 15;
    const int wr     = wave >> 1;
    const int wc     = wave & 1;
    const int rowBase = blockIdx.x * 128;
    const int colBase = blockIdx.y * 128;

    // Per-lane fragment base pointers (one 64B line per row per phase).
    const uint16_t* ap[4];
    const uint16_t* bp[4];
    #pragma unroll
    for (int t = 0; t < 4; ++t) {
        ap[t] = qb + (size_t)(rowBase + wr * 64 + t * 16 + lanelo) * DDIM + quad * 8;
        bp[t] = kb + (size_t)(colBase + wc * 64 + t * 16 + lanelo) * DDIM + quad * 8;
    }

    // Triple-buffered fragments: phase kk uses buf kk%3, prefetch kk+2 -> (kk+2)%3.
    bf16x8 af[3][4], bv[3][4];
    #pragma unroll
    for (int t = 0; t < 4; ++t) {
        af[0][t] = *(const bf16x8*)(ap[t]);
        bv[0][t] = *(const bf16x8*)(bp[t]);
        af[1][t] = *(const bf16x8*)(ap[t] + 32);
        bv[1][t] = *(const bf16x8*)(bp[t] + 32);
    }

    f32x4 acc[4][4];
    #pragma unroll
    for (int mt = 0; mt < 4; ++mt)
        #pragma unroll
        for (int nt = 0; nt < 4; ++nt)
            acc[mt][nt] = (f32x4){0.f, 0.f, 0.f, 0.f};

    #pragma unroll
    for (int kk = 0; kk < 8; ++kk) {
        const int cur = kk % 3;
        if (kk < 6) {
            const int nxt = (kk + 2) % 3;
            #pragma unroll
            for (int t = 0; t < 4; ++t) {
                af[nxt][t] = *(const bf16x8*)(ap[t] + (kk + 2) * 32);
                bv[nxt][t] = *(const bf16x8*)(bp[t] + (kk + 2) * 32);
            }
        }
        #pragma unroll
        for (int mt = 0; mt < 4; ++mt)
            #pragma unroll
            for (int nt = 0; nt < 4; ++nt)
                acc[mt][nt] = __builtin_amdgcn_mfma_f32_16x16x32_bf16(
                    af[cur][mt], bv[cur][nt], acc[mt][nt], 0, 0, 0);
    }

    // Epilogue: exp-sum, 16-lane shuffle reduce, one atomicAdd per row per wave.
    #pragma unroll
    for (int mt = 0; mt < 4; ++mt) {
        #pragma unroll
        for (int rg = 0; rg < 4; ++rg) {
            float s = 0.f;
            #pragma unroll
            for (int nt = 0; nt < 4; ++nt)
                s += exp2f(fmaf(acc[mt][nt][rg], K1, -K1));
            s += __shfl_xor(s, 1, 64);
            s += __shfl_xor(s, 2, 64);
            s += __shfl_xor(s, 4, 64);
            s += __shfl_xor(s, 8, 64);
            if (lanelo == 0)
                atomicAdd(&gpl[rowBase + wr * 64 + mt * 16 + quad * 4 + rg], s);
        }
    }
}

// Kernel 3: loss = M0 + log(L) - l_pos/T.
__global__ __launch_bounds__(256) void finalize_kernel(
    const float* __restrict__ gpl, const float* __restrict__ lpT,
    float* __restrict__ out)
{
    int t = blockIdx.x * 256 + threadIdx.x;
    if (t >= NROWS) return;
    out[t] = INV_T + __logf(gpl[t]) - lpT[t];
}

extern "C" void kernel_launch(void* const* d_in, const int* in_sizes, int n_in,
                              void* d_out, int out_size, void* d_ws, size_t ws_size,
                              hipStream_t stream) {
    const float* fq = (const float*)d_in[0];
    const float* fk = (const float*)d_in[1];
    char* ws = (char*)d_ws;
    // layout: qb 4MB | kb 4MB | lpT 32KB | gpl 32KB
    uint16_t* qb  = (uint16_t*)(ws);
    uint16_t* kb  = (uint16_t*)(ws + 4194304);
    float*    lpT = (float*)(ws + 8388608);
    float*    gpl = (float*)(ws + 8421376);

    norm_lpos_kernel<<<NROWS / 4, 256, 0, stream>>>(fq, fk, qb, kb, lpT, gpl);
    dim3 grid(NROWS / 128, NROWS / 128);
    nce_main_kernel<<<grid, 256, 0, stream>>>(qb, kb, gpl);
    finalize_kernel<<<NROWS / 256, 256, 0, stream>>>(gpl, lpT, (float*)d_out);
}